// Round 1
// baseline (792.722 us; speedup 1.0000x reference)
//
#include <hip/hip_runtime.h>

#define DD 40
#define SL 10
#define SLM1 9
#define ANUM 268
#define MROWS 32
#define ECH 8      // e-columns per LDS chunk
#define NCH 5      // chunks per step (40/8)

__global__ __launch_bounds__(256)
void star_fused_kernel(const int* __restrict__ X,
                       const int* __restrict__ T1,
                       const int* __restrict__ T2,
                       const float* __restrict__ Ew,
                       const float* __restrict__ Eb,
                       const float* __restrict__ Qw,
                       const float* __restrict__ Qb,
                       const float* __restrict__ Lw,
                       const float* __restrict__ Lb,
                       const float* __restrict__ Mw,
                       const float* __restrict__ Mb,
                       const float* __restrict__ Tw,
                       const float* __restrict__ Tb,
                       const float* __restrict__ emb,
                       float* __restrict__ out)
{
    __shared__ __align__(16) float pbuf[2][MROWS * DD];
    __shared__ __align__(16) float hbuf[2][MROWS * DD];
    __shared__ __align__(16) float qw_s[DD * DD];
    __shared__ __align__(16) float lb_s[DD * DD];
    __shared__ __align__(16) float lw_s[DD * ECH * DD]; // [d][e'][k], 51.2 KB

    const int tid   = threadIdx.x;
    const int blk   = blockIdx.x;
    const int m_own = tid >> 3;   // 0..31
    const int eg    = tid & 7;    // 0..7
    const int row0  = blk * MROWS;

    // zero-init state buffers (step 0 reads zeros)
    for (int i = tid; i < MROWS * DD; i += 256) {
        pbuf[0][i] = 0.0f;
        hbuf[0][i] = 0.0f;
    }
    __syncthreads();

    float preg[DD];
    float hreg[DD];

    for (int s = 0; s < SLM1; ++s) {
        const int rd = s & 1;
        const int wr = rd ^ 1;

        // ---- stage Qw[s] (1600 f) and Lb[s] (1600 f) into LDS ----
        {
            const float4* qsrc = (const float4*)(Qw + (size_t)s * 1600);
            const float4* lsrc = (const float4*)(Lb + (size_t)s * 1600);
            for (int i = tid; i < 400; i += 256) {
                ((float4*)qw_s)[i] = qsrc[i];
                ((float4*)lb_s)[i] = lsrc[i];
            }
        }
        __syncthreads();

        // ---- phase A: p1[m,j] = relu6(t*Ew + Eb + p0@Qw^T + Qb) ----
        #pragma unroll
        for (int i = 0; i < 5; ++i) {
            int pair = i * 256 + tid;          // 0..1279
            int m = pair / DD;
            int j = pair - m * DD;
            int row = row0 + m;
            float tv = (float)(T1[row * SLM1 + s] * 8 + T2[row * SLM1 + s]);
            float base = fmaf(tv, Ew[s * DD + j], Eb[s * DD + j] + Qb[s * DD + j]);
            const float* pm = &pbuf[rd][m * DD];
            const float* qj = &qw_s[j * DD];
            float s0 = base, s1 = 0.f, s2 = 0.f, s3 = 0.f;
            #pragma unroll
            for (int k = 0; k < DD; k += 4) {
                float4 pa = *(const float4*)(pm + k);
                float4 qa = *(const float4*)(qj + k);
                s0 = fmaf(pa.x, qa.x, s0);
                s1 = fmaf(pa.y, qa.y, s1);
                s2 = fmaf(pa.z, qa.z, s2);
                s3 = fmaf(pa.w, qa.w, s3);
            }
            float v = fminf(fmaxf((s0 + s1) + (s2 + s3), 0.0f), 6.0f);
            pbuf[wr][m * DD + j] = v;
        }
        __syncthreads();

        // ---- load this thread's p1 row and h row into registers ----
        #pragma unroll
        for (int k = 0; k < DD; k += 4) {
            float4 pv = *(const float4*)&pbuf[wr][m_own * DD + k];
            preg[k] = pv.x; preg[k + 1] = pv.y; preg[k + 2] = pv.z; preg[k + 3] = pv.w;
            float4 hv4 = *(const float4*)&hbuf[rd][m_own * DD + k];
            hreg[k] = hv4.x; hreg[k + 1] = hv4.y; hreg[k + 2] = hv4.z; hreg[k + 3] = hv4.w;
        }

        // ---- phase B: q GEMM + contraction, e in chunks of 8 ----
        for (int ec = 0; ec < NCH; ++ec) {
            // stage Lw rows (d*40 + ec*8 + e') for d=0..39, e'=0..7
            {
                const float4* src = (const float4*)(Lw + (size_t)s * 64000 + (size_t)ec * 320);
                for (int i = tid; i < 3200; i += 256) {
                    int d = i / 80;
                    int r = i - d * 80;
                    ((float4*)lw_s)[d * 80 + r] = src[d * 400 + r];
                }
            }
            __syncthreads();

            const int e = ec * ECH + eg;
            const float* lwb = lw_s + eg * DD;
            float acc = 0.0f;
            #pragma unroll
            for (int d = 0; d < DD; ++d) {
                const float* lr = lwb + d * (ECH * DD);
                float q0 = lb_s[d * DD + e];
                float q1 = 0.f, q2 = 0.f, q3 = 0.f;
                #pragma unroll
                for (int k = 0; k < DD; k += 4) {
                    float4 b4 = *(const float4*)(lr + k);
                    q0 = fmaf(preg[k + 0], b4.x, q0);
                    q1 = fmaf(preg[k + 1], b4.y, q1);
                    q2 = fmaf(preg[k + 2], b4.z, q2);
                    q3 = fmaf(preg[k + 3], b4.w, q3);
                }
                float qv = fminf(fmaxf((q0 + q1) + (q2 + q3), 0.0f), 6.0f);
                acc = fmaf(hreg[d], qv, acc);
            }

            // h1[m,e] = relu6(emb[aidx]@Mw[e,:] + Mb[e] + tt)
            {
                int row = row0 + m_own;
                int aidx = X[row * (SL * 4) + s * 4 + 3];
                const float* er = emb + (size_t)aidx * DD;
                const float* mr = Mw + (size_t)s * 1600 + (size_t)e * DD;
                float a0 = acc + Mb[s * DD + e], a1 = 0.f, a2 = 0.f, a3 = 0.f;
                #pragma unroll
                for (int k = 0; k < DD; k += 4) {
                    float4 ea = *(const float4*)(er + k);
                    float4 ma = *(const float4*)(mr + k);
                    a0 = fmaf(ea.x, ma.x, a0);
                    a1 = fmaf(ea.y, ma.y, a1);
                    a2 = fmaf(ea.z, ma.z, a2);
                    a3 = fmaf(ea.w, ma.w, a3);
                }
                float hv = fminf(fmaxf((a0 + a1) + (a2 + a3), 0.0f), 6.0f);
                hbuf[wr][m_own * DD + e] = hv;
            }
            __syncthreads();
        }
    }

    // ---- output: out[row, a] = h_final @ Tw[a,:] + Tb[a] ----
    // after s=8: wr was 1 -> final h in hbuf[1]
    float hfin[DD];
    #pragma unroll
    for (int k = 0; k < DD; k += 4) {
        float4 hv4 = *(const float4*)&hbuf[1][m_own * DD + k];
        hfin[k] = hv4.x; hfin[k + 1] = hv4.y; hfin[k + 2] = hv4.z; hfin[k + 3] = hv4.w;
    }
    const int row = row0 + m_own;
    float* orow = out + (size_t)row * ANUM;
    for (int ia = 0; ia < 34; ++ia) {
        int a = eg + ia * 8;
        if (a < ANUM) {
            const float* tw = Tw + (size_t)a * DD;
            float a0 = Tb[a], a1 = 0.f, a2 = 0.f, a3 = 0.f;
            #pragma unroll
            for (int k = 0; k < DD; k += 4) {
                float4 t4 = *(const float4*)(tw + k);
                a0 = fmaf(hfin[k + 0], t4.x, a0);
                a1 = fmaf(hfin[k + 1], t4.y, a1);
                a2 = fmaf(hfin[k + 2], t4.z, a2);
                a3 = fmaf(hfin[k + 3], t4.w, a3);
            }
            orow[a] = (a0 + a1) + (a2 + a3);
        }
    }
}

extern "C" void kernel_launch(void* const* d_in, const int* in_sizes, int n_in,
                              void* d_out, int out_size, void* d_ws, size_t ws_size,
                              hipStream_t stream) {
    const int*   X  = (const int*)  d_in[0];
    const int*   T1 = (const int*)  d_in[1];
    const int*   T2 = (const int*)  d_in[2];
    const float* Ew = (const float*)d_in[3];
    const float* Eb = (const float*)d_in[4];
    const float* Qw = (const float*)d_in[5];
    const float* Qb = (const float*)d_in[6];
    const float* Lw = (const float*)d_in[7];
    const float* Lb = (const float*)d_in[8];
    const float* Mw = (const float*)d_in[9];
    const float* Mb = (const float*)d_in[10];
    const float* Tw = (const float*)d_in[11];
    const float* Tb = (const float*)d_in[12];
    const float* em = (const float*)d_in[13];
    float* out = (float*)d_out;

    dim3 grid(8192 / MROWS);   // 256 blocks
    dim3 block(256);
    star_fused_kernel<<<grid, block, 0, stream>>>(X, T1, T2, Ew, Eb, Qw, Qb,
                                                  Lw, Lb, Mw, Mb, Tw, Tb, em, out);
}

// Round 2
// 107.816 us; speedup vs baseline: 7.3526x; 7.3526x over previous
//
#include <hip/hip_runtime.h>

#define DD 40
#define SLM1 9
#define ANUM 268
#define MB 32
#define EP 48
#define PSTR 72
#define HSTR 36
#define CH 4
#define NCHUNK 10

typedef __attribute__((ext_vector_type(8))) short short8;
typedef __attribute__((ext_vector_type(4))) float f32x4;

// ws layout (u16 units)
#define LW_U16 ((size_t)0)         // (s*40+d)*3072 + ct*1024(+512 frag2)
#define QW_U16 ((size_t)1105920)   // + s*3072
#define MW_U16 ((size_t)1133568)   // + s*3072 ; total 1161216 u16 = 2322432 B

__device__ __forceinline__ unsigned short f2bf(float f){
  unsigned int u = __float_as_uint(f);
  u += 0x7FFFu + ((u >> 16) & 1u);
  return (unsigned short)(u >> 16);
}
__device__ __forceinline__ float relu6f(float v){
  return fminf(fmaxf(v, 0.0f), 6.0f);
}

// Build MFMA B-fragments (lane-ordered, zero-padded K->64, e->48) for Lw/Qw/Mw.
__global__ __launch_bounds__(256)
void prep_frags(const float* __restrict__ Qw, const float* __restrict__ Lw,
                const float* __restrict__ Mw, unsigned short* __restrict__ ws)
{
  const int bid = blockIdx.x, tid = threadIdx.x;
  const float* base;
  unsigned short* dst;
  int nbase; // row offset multiplier: n = nbase + e
  if (bid < 360){
    int s = bid / 40, d = bid - s*40;
    base = Lw + (size_t)s*64000; nbase = d*DD;
    dst = ws + LW_U16 + (size_t)bid*3072;
  } else if (bid < 369){
    int s = bid - 360;
    base = Qw + (size_t)s*1600; nbase = 0;
    dst = ws + QW_U16 + (size_t)s*3072;
  } else {
    int s = bid - 369;
    base = Mw + (size_t)s*1600; nbase = 0;
    dst = ws + MW_U16 + (size_t)s*3072;
  }
  for (int i = tid; i < 3072; i += 256){
    int ct = i >> 10, r = i & 1023, frag = r >> 9, q = r & 511;
    int l = q >> 3, j = q & 7;
    int k = frag*32 + ((l >> 4) << 3) + j;   // B layout: k = 8*(l/16)+j (+32 for frag2)
    int e = ct*16 + (l & 15);                // col = l%16
    unsigned short v = 0;
    if (k < DD && e < DD) v = f2bf(base[(nbase + e)*DD + k]);
    dst[i] = v;
  }
}

__global__ __launch_bounds__(512)
void star_mfma_kernel(const int* __restrict__ X,
                      const int* __restrict__ T1,
                      const int* __restrict__ T2,
                      const float* __restrict__ Ew,
                      const float* __restrict__ Eb,
                      const float* __restrict__ Qb,
                      const float* __restrict__ Lb,
                      const float* __restrict__ Mb,
                      const float* __restrict__ Tw,
                      const float* __restrict__ Tb,
                      const float* __restrict__ emb,
                      const unsigned short* __restrict__ ws,
                      float* __restrict__ out)
{
  __shared__ __align__(16) unsigned short Bbuf[2][CH*3*1024]; // 49152 B
  __shared__ __align__(16) float red[4][MB*EP];               // 24576 B
  __shared__ __align__(16) float hT[2][DD*HSTR];              // 11520 B
  __shared__ __align__(16) unsigned short pbuf[2][MB*PSTR];   // 9216 B
  __shared__ __align__(16) unsigned short qwfrag[3*1024];     // 6144 B
  __shared__ __align__(16) unsigned short mwfrag[3*1024];     // 6144 B
  __shared__ __align__(16) float lb_s[DD*EP];                 // 7680 B
  __shared__ __align__(16) unsigned short ae_s[MB*PSTR];      // 4608 B
  __shared__ __align__(16) float ew_s[EP], eb_s[EP], qb_s[EP], mb_s[EP];
  __shared__ float tvec[MB];

  const int tid = threadIdx.x;
  const int w = tid >> 6, l = tid & 63;
  const int col = l & 15, rg = l >> 4;
  const int rt = w & 1, dpar = w >> 1;
  const int row0 = blockIdx.x * MB;

  // ---- one-time zero init (pads must stay zero) ----
  {
    unsigned int* p32 = (unsigned int*)&pbuf[0][0];
    for (int i = tid; i < 2*MB*PSTR/2; i += 512) p32[i] = 0u;
    unsigned int* a32 = (unsigned int*)&ae_s[0];
    for (int i = tid; i < MB*PSTR/2; i += 512) a32[i] = 0u;
    for (int i = tid; i < 2*DD*HSTR; i += 512) (&hT[0][0])[i] = 0.0f;
    for (int i = tid; i < DD*EP; i += 512) lb_s[i] = 0.0f;
    for (int i = tid; i < EP; i += 512){ ew_s[i]=0.f; eb_s[i]=0.f; qb_s[i]=0.f; mb_s[i]=0.f; }
  }
  __syncthreads();

  for (int s = 0; s < SLM1; ++s){
    const int prd = s & 1, pwr = prd ^ 1;
    const int hrd = s & 1, hwr = hrd ^ 1;

    // ---- stage per-step tables ----
    {
      const unsigned int* qsrc = (const unsigned int*)(ws + QW_U16 + (size_t)s*3072);
      unsigned int* qdst = (unsigned int*)qwfrag;
      for (int i = tid; i < 1536; i += 512) qdst[i] = qsrc[i];
      const unsigned int* msrc = (const unsigned int*)(ws + MW_U16 + (size_t)s*3072);
      unsigned int* mdst = (unsigned int*)mwfrag;
      for (int i = tid; i < 1536; i += 512) mdst[i] = msrc[i];
      for (int i = tid; i < 1600; i += 512){
        int dq = i / DD, e = i - dq*DD;
        lb_s[dq*EP + e] = Lb[(size_t)s*1600 + i];
      }
      if (tid < DD){
        ew_s[tid] = Ew[s*DD + tid];
        eb_s[tid] = Eb[s*DD + tid];
        qb_s[tid] = Qb[s*DD + tid];
        mb_s[tid] = Mb[s*DD + tid];
      }
      if (tid < MB){
        int r = row0 + tid;
        tvec[tid] = (float)(T1[r*SLM1 + s]*8 + T2[r*SLM1 + s]);
      }
      if (tid < 320){
        int m = tid / 10, q4 = tid - m*10;
        int aidx = X[(size_t)(row0 + m)*40 + s*4 + 3];
        float4 v4 = *(const float4*)(emb + (size_t)aidx*DD + q4*4);
        unsigned short* dstp = &ae_s[m*PSTR + q4*4];
        dstp[0] = f2bf(v4.x); dstp[1] = f2bf(v4.y);
        dstp[2] = f2bf(v4.z); dstp[3] = f2bf(v4.w);
      }
      // stage chunk 0 -> Bbuf[0]
      const uint4* src = (const uint4*)(ws + LW_U16 + (size_t)(s*40)*3072);
      uint4* dst = (uint4*)&Bbuf[0][0];
      uint4 v0 = src[(w*3+0)*64 + l];
      uint4 v1 = src[(w*3+1)*64 + l];
      uint4 v2 = src[(w*3+2)*64 + l];
      dst[(w*3+0)*64 + l] = v0;
      dst[(w*3+1)*64 + l] = v1;
      dst[(w*3+2)*64 + l] = v2;
    }
    __syncthreads();

    // ---- phase A: p1 = relu6(t*Ew + Eb + Qb + p0@Qw^T)  [6 waves, mfma] ----
    if (w < 6){
      const int rtA = w & 1, ctA = w >> 1;
      short8 a1 = *(const short8*)&pbuf[prd][(rtA*16 + col)*PSTR + (rg << 3)];
      short8 a2 = *(const short8*)&pbuf[prd][(rtA*16 + col)*PSTR + 32 + (rg << 3)];
      const unsigned short* qb_ = &qwfrag[ctA*1024];
      short8 b1 = ((const short8*)qb_)[l];
      short8 b2 = ((const short8*)(qb_ + 512))[l];
      f32x4 c = {0.f,0.f,0.f,0.f};
      c = __builtin_amdgcn_mfma_f32_16x16x32_bf16(a1, b1, c, 0, 0, 0);
      c = __builtin_amdgcn_mfma_f32_16x16x32_bf16(a2, b2, c, 0, 0, 0);
      #pragma unroll
      for (int i = 0; i < 4; ++i){
        int m = rtA*16 + rg*4 + i;
        int j = ctA*16 + col;
        float v = relu6f(c[i] + tvec[m]*ew_s[j] + eb_s[j] + qb_s[j]);
        if (j < DD) pbuf[pwr][m*PSTR + j] = f2bf(v);
      }
    }
    __syncthreads();

    // ---- phase B: q GEMM + h0 contraction ----
    short8 pa1 = *(const short8*)&pbuf[pwr][(rt*16 + col)*PSTR + (rg << 3)];
    short8 pa2 = *(const short8*)&pbuf[pwr][(rt*16 + col)*PSTR + 32 + (rg << 3)];
    float tt[3][4];
    #pragma unroll
    for (int ct = 0; ct < 3; ++ct)
      #pragma unroll
      for (int i = 0; i < 4; ++i) tt[ct][i] = 0.0f;

    for (int c = 0; c < NCHUNK; ++c){
      uint4 st0, st1, st2;
      const bool havestage = (c + 1 < NCHUNK);
      if (havestage){
        const uint4* src = (const uint4*)(ws + LW_U16 + (size_t)(s*40 + (c+1)*CH)*3072);
        st0 = src[(w*3+0)*64 + l];
        st1 = src[(w*3+1)*64 + l];
        st2 = src[(w*3+2)*64 + l];
      }
      const int d = c*CH + dpar;
      f32x4 hv = *(const f32x4*)&hT[hrd][d*HSTR + rt*16 + rg*4];
      const unsigned short* bchunk = &Bbuf[c & 1][0];
      #pragma unroll
      for (int ct = 0; ct < 3; ++ct){
        const unsigned short* bb = bchunk + (dpar*3 + ct)*1024;
        short8 b1 = ((const short8*)bb)[l];
        short8 b2 = ((const short8*)(bb + 512))[l];
        f32x4 q = {0.f,0.f,0.f,0.f};
        q = __builtin_amdgcn_mfma_f32_16x16x32_bf16(pa1, b1, q, 0, 0, 0);
        q = __builtin_amdgcn_mfma_f32_16x16x32_bf16(pa2, b2, q, 0, 0, 0);
        #pragma unroll
        for (int i = 0; i < 4; ++i){
          int e = ct*16 + col;
          float qv = relu6f(q[i] + lb_s[d*EP + e]);
          tt[ct][i] = fmaf(hv[i], qv, tt[ct][i]);
        }
      }
      if (havestage){
        uint4* dst = (uint4*)&Bbuf[(c+1) & 1][0];
        dst[(w*3+0)*64 + l] = st0;
        dst[(w*3+1)*64 + l] = st1;
        dst[(w*3+2)*64 + l] = st2;
      }
      __syncthreads();
    }

    // ---- tt partials -> red ----
    #pragma unroll
    for (int ct = 0; ct < 3; ++ct)
      #pragma unroll
      for (int i = 0; i < 4; ++i)
        red[dpar][(rt*16 + rg*4 + i)*EP + ct*16 + col] = tt[ct][i];
    __syncthreads();

    // ---- phase C: h1 = relu6(ae@Mw^T + Mb + tt)  [6 waves, mfma] ----
    if (w < 6){
      const int rtC = w & 1, ctC = w >> 1;
      short8 a1 = *(const short8*)&ae_s[(rtC*16 + col)*PSTR + (rg << 3)];
      short8 a2 = *(const short8*)&ae_s[(rtC*16 + col)*PSTR + 32 + (rg << 3)];
      const unsigned short* mb_ = &mwfrag[ctC*1024];
      short8 b1 = ((const short8*)mb_)[l];
      short8 b2 = ((const short8*)(mb_ + 512))[l];
      f32x4 c = {0.f,0.f,0.f,0.f};
      c = __builtin_amdgcn_mfma_f32_16x16x32_bf16(a1, b1, c, 0, 0, 0);
      c = __builtin_amdgcn_mfma_f32_16x16x32_bf16(a2, b2, c, 0, 0, 0);
      #pragma unroll
      for (int i = 0; i < 4; ++i){
        int m = rtC*16 + rg*4 + i;
        int e = ctC*16 + col;
        float v = c[i] + mb_s[e]
                + red[0][m*EP + e] + red[1][m*EP + e]
                + red[2][m*EP + e] + red[3][m*EP + e];
        v = relu6f(v);
        if (e < DD) hT[hwr][e*HSTR + m] = v;
      }
    }
    __syncthreads();
  }

  // ---- output: out = h @ Tw^T + Tb  (h in hT[1]) ----
  {
    const int m = tid >> 4, as = tid & 15;
    float hr[DD];
    #pragma unroll
    for (int k = 0; k < DD; ++k) hr[k] = hT[1][k*HSTR + m];
    float* orow = out + (size_t)(row0 + m)*ANUM;
    for (int ia = 0; ia < 17; ++ia){
      int a = as + (ia << 4);
      if (a < ANUM){
        const float* tw = Tw + (size_t)a*DD;
        float s0 = Tb[a], s1 = 0.f, s2 = 0.f, s3 = 0.f;
        #pragma unroll
        for (int k = 0; k < DD; k += 4){
          float4 t4 = *(const float4*)(tw + k);
          s0 = fmaf(hr[k+0], t4.x, s0);
          s1 = fmaf(hr[k+1], t4.y, s1);
          s2 = fmaf(hr[k+2], t4.z, s2);
          s3 = fmaf(hr[k+3], t4.w, s3);
        }
        orow[a] = (s0 + s1) + (s2 + s3);
      }
    }
  }
}

extern "C" void kernel_launch(void* const* d_in, const int* in_sizes, int n_in,
                              void* d_out, int out_size, void* d_ws, size_t ws_size,
                              hipStream_t stream) {
  const int*   X  = (const int*)  d_in[0];
  const int*   T1 = (const int*)  d_in[1];
  const int*   T2 = (const int*)  d_in[2];
  const float* Ew = (const float*)d_in[3];
  const float* Eb = (const float*)d_in[4];
  const float* Qw = (const float*)d_in[5];
  const float* Qb = (const float*)d_in[6];
  const float* Lw = (const float*)d_in[7];
  const float* Lb = (const float*)d_in[8];
  const float* Mw = (const float*)d_in[9];
  const float* Mb = (const float*)d_in[10];
  const float* Tw = (const float*)d_in[11];
  const float* Tb = (const float*)d_in[12];
  const float* em = (const float*)d_in[13];
  unsigned short* ws = (unsigned short*)d_ws;
  float* out = (float*)d_out;

  prep_frags<<<dim3(378), dim3(256), 0, stream>>>(Qw, Lw, Mw, ws);
  star_mfma_kernel<<<dim3(8192 / MB), dim3(512), 0, stream>>>(
      X, T1, T2, Ew, Eb, Qb, Lb, Mb, Tw, Tb, em, ws, out);
}